// Round 1
// 93.682 us; speedup vs baseline: 1.0024x; 1.0024x over previous
//
#include <hip/hip_runtime.h>
#include <math.h>

// One thread per TWO batch elements as a packed float2 (v_pk_* fp32).
// R11 (this round):
//  - LDS table of per-iteration Adam bias-correction scalars A(t)=lr'*rcp(1-b1^t)*sqrt(1-b2^t),
//    C(t)=lr'*rcp(1-b1^t)*1e8 -> removes 2 transcendentals + ~6 VALU per iter.
//  - log2-space channel state (Adam scale-invariance, g kept in ch-space):
//    exp(ch) -> v_exp_f32 directly, no per-iter *log2e muls; Sa/x_a folded.
//  - direct s1 accumulation (no K/KU combine), fused clamp min(rsq*A, C).
//  - dwordx4 loads for X/Y rows, dwordx4 stores, loads issued before uniform setup.
// Retains: cubic-poly per-lambda collapse, batched product-reciprocal,
// clamped-rsqrt Adam, diagonal fast path, dense fallback.

typedef float v2f __attribute__((ext_vector_type(2)));
typedef float f4a __attribute__((ext_vector_type(4), aligned(4)));
typedef float f2a __attribute__((ext_vector_type(2), aligned(4)));

__device__ __forceinline__ float frcp(float x)  { return __builtin_amdgcn_rcpf(x); }
__device__ __forceinline__ float fsqrt_(float x){ return __builtin_amdgcn_sqrtf(x); }
__device__ __forceinline__ float fexp2_(float x){ return __builtin_amdgcn_exp2f(x); }  // v_exp_f32 = 2^x
__device__ __forceinline__ float frsq_(float x) { return __builtin_amdgcn_rsqf(x); }
__device__ __forceinline__ float fexp(float x)  { return __expf(x); }

__device__ __forceinline__ v2f vrcp(v2f x){ v2f r; r.x = frcp(x.x); r.y = frcp(x.y); return r; }
__device__ __forceinline__ v2f vsqrt(v2f x){ v2f r; r.x = fsqrt_(x.x); r.y = fsqrt_(x.y); return r; }
__device__ __forceinline__ v2f vrsq(v2f x){ v2f r; r.x = frsq_(x.x); r.y = frsq_(x.y); return r; }
__device__ __forceinline__ v2f vexp(v2f x){ v2f r; r.x = fexp(x.x); r.y = fexp(x.y); return r; }
__device__ __forceinline__ v2f vexp2(v2f x){ v2f r; r.x = fexp2_(x.x); r.y = fexp2_(x.y); return r; }
__device__ __forceinline__ v2f vminc(v2f x, float c){
    v2f r; r.x = fminf(x.x, c); r.y = fminf(x.y, c); return r;
}

#define TBL_N 512

__global__ __launch_bounds__(64)
void pe_kernel(const float* __restrict__ X,      // (B,5,5)
               const float* __restrict__ Y,      // (B,5)
               const float* __restrict__ ch0p,   // (B,1,3)
               const float* __restrict__ pf,     // (14,)
               const float* __restrict__ x_a,    // (3,)
               const float* __restrict__ s_a_inv,// (3,3)
               const float* __restrict__ s_e_inv,// (5,5)
               const int*   __restrict__ n_iter, // (1,)
               float* __restrict__ out,          // (B,9)
               int B, int n0)                    // n0 = ceil(B/2)
{
    __shared__ f2a tab[TBL_N];   // (A(t), C(t)) per iteration

    const int bt = blockIdx.x * blockDim.x + threadIdx.x;
    const bool active = (bt < n0);
    const int b = active ? bt : 0;          // clamp so inactive lanes load valid addrs
    const bool valid1 = (b + n0) < B;
    const int e0 = b;
    const int e1 = valid1 ? (b + n0) : b;

    // ---- issue the per-element global loads FIRST (hide HBM latency under setup) ----
    f4a xr0[5], xr1[5];
    const float* xb0 = X + (size_t)e0 * 25;
    const float* xb1 = X + (size_t)e1 * 25;
#pragma unroll
    for (int l = 0; l < 5; ++l) {
        xr0[l] = *reinterpret_cast<const f4a*>(xb0 + l * 5);   // cols 0..3
        xr1[l] = *reinterpret_cast<const f4a*>(xb1 + l * 5);
    }
    const f4a y40 = *reinterpret_cast<const f4a*>(Y + (size_t)e0 * 5);
    const f4a y41 = *reinterpret_cast<const f4a*>(Y + (size_t)e1 * 5);
    const float y4e0 = Y[(size_t)e0 * 5 + 4];
    const float y4e1 = Y[(size_t)e1 * 5 + 4];
    const f2a c010 = *reinterpret_cast<const f2a*>(ch0p + (size_t)e0 * 3);
    const f2a c011 = *reinterpret_cast<const f2a*>(ch0p + (size_t)e1 * 3);
    const float c2e0 = ch0p[(size_t)e0 * 3 + 2];
    const float c2e1 = ch0p[(size_t)e1 * 3 + 2];

    const int T = n_iter[0];

    const float LAM2E  = 1.4426950408889634f;   // log2(e)
    const float INVL2E = 0.6931471805599453f;   // ln(2)
    const float LRc = 0.02f;
    const float LRL = LRc * LAM2E;              // step size in log2-space
    const float LN999 = -0.0010004874458f;      // ln(float(0.999)), high precision

    // ---- per-iteration Adam scalars -> LDS table (lane-parallel, one time) ----
    {
        const int tn = (T < TBL_N) ? T : TBL_N;
        for (int t = (int)threadIdx.x; t < tn; t += 64) {
            const float tf = (float)(t + 1);
            const float p1t = __powf(0.9f, tf);
            const float om2 = -expm1f(tf * LN999);      // 1 - 0.999^t, no cancellation
            const float im  = LRL * frcp(1.0f - p1t);   // lr' / (1 - b1^t)
            f2a e; e.x = im * fsqrt_(om2); e.y = im * 1e8f;
            tab[t] = e;
        }
    }
    __syncthreads();
    if (!active) return;

    const float lam[5] = {-0.275f, 0.025f, 0.5f, 0.7f, 1.15f};

    float pfv[14];
#pragma unroll
    for (int i = 0; i < 14; ++i) pfv[i] = pf[i];

    const float xa0 = x_a[0], xa1 = x_a[1], xa2 = x_a[2];

    float Sa[3][3];
#pragma unroll
    for (int i = 0; i < 3; ++i)
#pragma unroll
        for (int j = 0; j < 3; ++j)
            Sa[i][j] = 0.5f * (s_a_inv[i*3+j] + s_a_inv[j*3+i]);

    float Se[5][5];
#pragma unroll
    for (int i = 0; i < 5; ++i)
#pragma unroll
        for (int j = 0; j < 5; ++j)
            Se[i][j] = 0.5f * (s_e_inv[i*5+j] + s_e_inv[j*5+i]);

    // Wave-uniform structure check.
    bool diag = true;
#pragma unroll
    for (int i = 0; i < 5; ++i)
#pragma unroll
        for (int j = 0; j < 5; ++j)
            if (i != j && Se[i][j] != 0.0f) diag = false;
#pragma unroll
    for (int i = 0; i < 3; ++i)
#pragma unroll
        for (int j = 0; j < 3; ++j)
            if (i != j && Sa[i][j] != 0.0f) diag = false;

    // Iteration-invariant optics constants (uniform).
    const float A0   = 0.0045f, Bb0 = 0.0012f;
    const float Anap = pfv[12] * 0.005f;
    const float Bnap = pfv[13] * 0.005f;
    const float c1   = pfv[7] * 0.089f;
    const float c2   = pfv[8] * 0.1245f;
    const float c22  = 2.0f * c2;
    float Aph[5], Acd[5], Bph[5];
#pragma unroll
    for (int l = 0; l < 5; ++l) {
        Aph[l] = pfv[0] * 0.05f * (1.0f + pfv[1] * 0.1f * lam[l] + pfv[2] * 0.01f);
        Acd[l] = pfv[5] * 0.1f * fexp(-pfv[6] * 1.7f * lam[l]);
        Bph[l] = pfv[3] * 0.001f * (1.0f + pfv[4] * 0.05f * lam[l]);
    }

    // Per-element iteration-invariant data, packed (elem0, elem1).
    v2f E[5], Yv[5], x3[5];
#pragma unroll
    for (int l = 0; l < 5; ++l) {
        const float Ed0 = xr0[l].x, Ef0 = xr0[l].y;
        const float Ed1 = xr1[l].x, Ef1 = xr1[l].y;
        x3[l].x = xr0[l].w;  x3[l].y = xr1[l].w;
        E[l].x  = (Ed0 + 0.5f * Ef0) * frcp(Ed0 + Ef0);
        E[l].y  = (Ed1 + 0.5f * Ef1) * frcp(Ed1 + Ef1);
        Yv[l].x = (l < 4) ? y40[l] : y4e0;
        Yv[l].y = (l < 4) ? y41[l] : y4e1;
    }

    v2f ch[3], mm[3], vv[3];
    ch[0].x = c010.x;  ch[0].y = c011.x;
    ch[1].x = c010.y;  ch[1].y = c011.y;
    ch[2].x = c2e0;    ch[2].y = c2e1;
#pragma unroll
    for (int k = 0; k < 3; ++k) { mm[k] = (v2f)0.0f; vv[k] = (v2f)0.0f; }

    const float B1c = 0.9f,   oB1 = 1.0f - 0.9f;
    const float B2c = 0.999f, oB2 = 1.0f - 0.999f;
    const float EPSc = 1e-8f;

    v2f chla, nap, cdom;   // natural-exp channel values for epilogue

    if (diag) {
        // ---------- fast path: diagonal Sym(Se), Sym(Sa) ----------
        // Channel state in log2-space: ch' = log2e * ch. Gradient g stays in
        // ch-space (Adam m/sqrt(v) is invariant to g scaling); the step uses
        // LR' = log2e*LR folded into the table. exp(ch) == exp2(ch').
        ch[0] *= LAM2E;  ch[1] *= LAM2E;  ch[2] *= LAM2E;

        const float SaD0 = Sa[0][0], SaD1 = Sa[1][1], SaD2 = Sa[2][2];
        const float SaD0i = SaD0 * INVL2E, SaD1i = SaD1 * INVL2E, SaD2i = SaD2 * INVL2E;
        const float cxa0 = SaD0 * xa0, cxa1 = SaD1 * xa1, cxa2 = SaD2 * xa2;
        const float ABn  = Anap + Bnap;
        const float AB0c = A0 + Bb0;

        // Per-lambda uniform constants + per-element cubic coefficients of
        // phi(u) = (c1+2c2 u)((c1 u + c2 u^2) E2S - YES).
        float AB2s[5], Bph2s[5], Acd2s[5];
        v2f d3[5], d2[5], d1[5], d0[5];
        const float k3 = 2.0f * c2 * c2;
        const float k2 = 3.0f * c1 * c2;
        const float k1 = c1 * c1;
#pragma unroll
        for (int l = 0; l < 5; ++l) {
            AB2s[l]  = Aph[l] + Bph[l];
            Bph2s[l] = Bph[l];
            Acd2s[l] = Acd[l];
            const v2f E2S = (Se[l][l] * E[l]) * E[l];
            const v2f YES = (Se[l][l] * E[l]) * Yv[l];
            d3[l] = k3 * E2S;
            d2[l] = k2 * E2S;
            d1[l] = k1 * E2S - c22 * YES;
            d0[l] = -c1 * YES;
        }

        for (int t = 0; t < T; ++t) {
            float Asc, Csc;
            if (t < TBL_N) {
                const f2a ac = tab[t];
                Asc = ac.x; Csc = ac.y;
            } else {   // wave-uniform, only for absurd T
                const float tf = (float)(t + 1);
                const float p1t = __powf(0.9f, tf);
                const float om2 = -expm1f(tf * LN999);
                const float im  = LRL * frcp(1.0f - p1t);
                Asc = im * fsqrt_(om2); Csc = im * 1e8f;
            }

            const v2f xch = vexp2(ch[0]);   // chla
            const v2f xnp = vexp2(ch[1]);   // nap
            const v2f xcd = vexp2(ch[2]);   // cdom

            const v2f btv = Bb0  + Bnap * xnp;
            const v2f ctv = AB0c + ABn  * xnp;

            // Stage s, bb per lambda.
            v2f sv[5], bbv[5];
#pragma unroll
            for (int l = 0; l < 5; ++l) {
                sv[l]  = AB2s[l] * xch + (Acd2s[l] * xcd + ctv);
                bbv[l] = Bph2s[l] * xch + btv;
            }

            // Batched reciprocal: 1/s_i = (prod_{j!=i}) * rcp(prod all).
            const v2f P1 = sv[0] * sv[1];
            const v2f P2 = P1 * sv[2];
            const v2f P3 = P2 * sv[3];
            const v2f Pa = P3 * sv[4];
            const v2f S3 = sv[4] * sv[3];
            const v2f S2 = S3 * sv[2];
            const v2f S1 = S2 * sv[1];
            const v2f rP = vrcp(Pa);
            v2f inv[5];
            inv[0] = S1 * rP;
            inv[1] = (sv[0] * S2) * rP;
            inv[2] = (P1 * S3) * rP;
            inv[3] = (P2 * sv[4]) * rP;
            inv[4] = P3 * rP;

            v2f s0p = (v2f)0.0f, s0m = (v2f)0.0f;
            v2f s1a = (v2f)0.0f, s1b = (v2f)0.0f;
            v2f s2v = (v2f)0.0f;
#pragma unroll
            for (int l = 0; l < 5; ++l) {
                const v2f u   = bbv[l] * inv[l];
                const v2f phi = ((d3[l] * u + d2[l]) * u + d1[l]) * u + d0[l];
                const v2f k   = inv[l] * phi;
                const v2f ku  = k * u;
                s0p += Bph2s[l] * k;
                s0m += AB2s[l]  * ku;
                s1a += Bnap * k;
                s1b += ABn  * ku;
                s2v += Acd2s[l] * ku;
            }
            const v2f s0 = s0p - s0m;
            const v2f s1 = s1a - s1b;

            // g in ch-space: SaD*(ch - xa) + exp(ch)*s  with ch = ch'/log2e folded.
            v2f gs[3];
            gs[0] = SaD0i * ch[0] + (xch * s0 - cxa0);
            gs[1] = SaD1i * ch[1] + (xnp * s1 - cxa1);
            gs[2] = SaD2i * ch[2] - (xcd * s2v + cxa2);

#pragma unroll
            for (int k = 0; k < 3; ++k) {
                const v2f g = gs[k];
                mm[k] = B1c * mm[k] + oB1 * g;
                vv[k] = B2c * vv[k] + oB2 * (g * g);
                const v2f dv = vminc(vrsq(vv[k]) * Asc, Csc);
                ch[k] -= mm[k] * dv;
            }
        }

        chla = vexp2(ch[0]);  nap = vexp2(ch[1]);  cdom = vexp2(ch[2]);
        ch[0] *= INVL2E;   // back to natural-log space for output o[0]
    } else {
        // ---------- general path (dense Sym(Se)/Sym(Sa)) ----------
        float p1 = 1.0f, p2 = 1.0f;
        const float LR = 0.02f;
        for (int t = 0; t < T; ++t) {
            p1 *= B1c; p2 *= B2c;
            const float im   = frcp(1.0f - p1);
            const float sqiv = fsqrt_(frcp(1.0f - p2));
            const float lrim = LR * im;

            const v2f chl = vexp(ch[0]);
            const v2f np  = vexp(ch[1]);
            const v2f cd  = vexp(ch[2]);

            const v2f dd0 = ch[0] - xa0, dd1 = ch[1] - xa1, dd2 = ch[2] - xa2;
            v2f g0 = Sa[0][0]*dd0 + Sa[0][1]*dd1 + Sa[0][2]*dd2;
            v2f g1 = Sa[1][0]*dd0 + Sa[1][1]*dd1 + Sa[1][2]*dd2;
            v2f g2 = Sa[2][0]*dd0 + Sa[2][1]*dd1 + Sa[2][2]*dd2;

            const v2f da1 = Anap * np;
            const v2f db1 = Bnap * np;

            v2f av[5], bv[5], wv[5], rv[5];
#pragma unroll
            for (int l = 0; l < 5; ++l) {
                const v2f da0 = Aph[l] * chl;
                const v2f db0 = Bph[l] * chl;
                const v2f da2 = Acd[l] * cd;
                const v2f a   = A0  + da0 + da2 + da1;
                const v2f bb  = Bb0 + db0 + db1;
                const v2f inv_s = vrcp(a + bb);
                const v2f u     = bb * inv_s;
                const v2f rrs   = (c1 + c2 * u) * u;
                av[l] = a;
                bv[l] = bb;
                rv[l] = rrs * E[l] - Yv[l];
                wv[l] = (c1 + c22 * u) * E[l] * inv_s * inv_s;
            }

            v2f s0 = (v2f)0.0f, s1 = (v2f)0.0f, s2 = (v2f)0.0f;
#pragma unroll
            for (int i = 0; i < 5; ++i) {
                const v2f q = Se[i][0]*rv[0] + Se[i][1]*rv[1] + Se[i][2]*rv[2]
                            + Se[i][3]*rv[3] + Se[i][4]*rv[4];
                const v2f h = wv[i] * q;
                s0 += h * (Bph[i] * av[i] - Aph[i] * bv[i]);
                s1 += h * (Bnap   * av[i] - Anap   * bv[i]);
                s2 += h * (Acd[i] * bv[i]);
            }
            g0 += chl * s0;
            g1 += np  * s1;
            g2 -= cd  * s2;

            const v2f gsv[3] = {g0, g1, g2};
#pragma unroll
            for (int k = 0; k < 3; ++k) {
                const v2f g = gsv[k];
                mm[k] = B1c * mm[k] + oB1 * g;
                vv[k] = B2c * vv[k] + oB2 * (g * g);
                const v2f den = vsqrt(vv[k]) * sqiv + EPSc;
                ch[k] -= (lrim * mm[k]) * vrcp(den);
            }
        }
        chla = vexp(ch[0]);  nap = vexp(ch[1]);  cdom = vexp(ch[2]);
    }

    // Epilogue
    const float kdscale = pfv[9] * 0.9f + pfv[10] * 0.1f;
    const float lam3[3] = {0.025f, 0.5f, 1.15f};

#pragma unroll
    for (int ee = 0; ee < 2; ++ee) {
        if (ee == 1 && !valid1) break;
        const int e = ee ? e1 : e0;
        const float chl = ee ? chla.y : chla.x;
        const float np  = ee ? nap.y  : nap.x;
        const float cd  = ee ? cdom.y : cdom.x;

        float o[9];
        o[0] = ee ? ch[0].y : ch[0].x;
#pragma unroll
        for (int l = 0; l < 5; ++l) {
            const float a  = A0  + Aph[l]*chl + Acd[l]*cd + Anap*np;
            const float bb = Bb0 + Bph[l]*chl + Bnap*np;
            const float xx = ee ? x3[l].y : x3[l].x;
            const float sig = frcp(1.0f + fexp(-xx));
            const float mu  = 0.5f + 0.5f * sig;
            o[1 + l] = (a + bb) * frcp(mu) * kdscale;
        }
#pragma unroll
        for (int j = 0; j < 3; ++j) {
            const float bph = pfv[3] * 0.001f * (1.0f + pfv[4] * 0.05f * lam3[j]);
            o[6 + j] = pfv[11] * (bph * chl + Bnap * np);
        }
        f4a w0, w1;
        w0.x = o[0]; w0.y = o[1]; w0.z = o[2]; w0.w = o[3];
        w1.x = o[4]; w1.y = o[5]; w1.z = o[6]; w1.w = o[7];
        *reinterpret_cast<f4a*>(out + (size_t)e*9)     = w0;
        *reinterpret_cast<f4a*>(out + (size_t)e*9 + 4) = w1;
        out[(size_t)e*9 + 8] = o[8];
    }
}

extern "C" void kernel_launch(void* const* d_in, const int* in_sizes, int n_in,
                              void* d_out, int out_size, void* d_ws, size_t ws_size,
                              hipStream_t stream) {
    const float* X   = (const float*)d_in[0];
    const float* Y   = (const float*)d_in[1];
    const float* ch0 = (const float*)d_in[2];
    const float* pf  = (const float*)d_in[3];
    const float* xa  = (const float*)d_in[4];
    const float* sa  = (const float*)d_in[5];
    const float* se  = (const float*)d_in[6];
    const int*   ni  = (const int*)d_in[7];
    float* out = (float*)d_out;

    const int B  = in_sizes[0] / 25;
    const int n0 = (B + 1) / 2;
    const int block = 64;
    const int grid = (n0 + block - 1) / block;
    hipLaunchKernelGGL(pe_kernel, dim3(grid), dim3(block), 0, stream,
                       X, Y, ch0, pf, xa, sa, se, ni, out, B, n0);
}